// Round 1
// baseline (199.537 us; speedup 1.0000x reference)
//
#include <hip/hip_runtime.h>

// Problem dims (fixed by reference)
#define B_DIM 32
#define N_DIM 4096
#define PATCH_DIM 1024
#define TEXT_DIM 768
#define HIDDEN 512

// ---------------------------------------------------------------------------
// Kernel A: t[b,h] = text[b,:] . W_text[h,:] + b_text[h]   (one block per b)
//           bias[b] = t[b,:] . b_patch
// ---------------------------------------------------------------------------
__global__ __launch_bounds__(256) void text_proj_kernel(
    const float* __restrict__ text,     // [B, TEXT_DIM]
    const float* __restrict__ W_text,   // [HIDDEN, TEXT_DIM]
    const float* __restrict__ b_text,   // [HIDDEN]
    const float* __restrict__ b_patch,  // [HIDDEN]
    float* __restrict__ t_out,          // [B, HIDDEN]
    float* __restrict__ bias_out)       // [B]
{
    const int b = blockIdx.x;
    const float* tx = text + (size_t)b * TEXT_DIM;

    __shared__ float t_sh[HIDDEN];

    // Each thread computes 2 h-values (256 threads, HIDDEN=512)
    for (int h = threadIdx.x; h < HIDDEN; h += 256) {
        const float* w = W_text + (size_t)h * TEXT_DIM;
        float acc = 0.f;
        #pragma unroll 4
        for (int j = 0; j < TEXT_DIM; j += 4) {
            float4 a  = *reinterpret_cast<const float4*>(tx + j);
            float4 ww = *reinterpret_cast<const float4*>(w + j);
            acc += a.x * ww.x + a.y * ww.y + a.z * ww.z + a.w * ww.w;
        }
        float val = acc + b_text[h];
        t_sh[h] = val;
        t_out[(size_t)b * HIDDEN + h] = val;
    }
    __syncthreads();

    // bias[b] = dot(t_sh, b_patch) — block reduce
    float partial = 0.f;
    for (int h = threadIdx.x; h < HIDDEN; h += 256)
        partial += t_sh[h] * b_patch[h];

    // wave reduce (64 lanes)
    #pragma unroll
    for (int off = 32; off > 0; off >>= 1)
        partial += __shfl_xor(partial, off, 64);

    __shared__ float wsum[4];
    const int lane = threadIdx.x & 63;
    const int wid  = threadIdx.x >> 6;
    if (lane == 0) wsum[wid] = partial;
    __syncthreads();
    if (threadIdx.x == 0)
        bias_out[b] = wsum[0] + wsum[1] + wsum[2] + wsum[3];
}

// ---------------------------------------------------------------------------
// Kernel B: v[b,d] = sum_h t[b,h] * W_patch[h,d]   (one block per b)
// Coalesced over d (consecutive threads -> consecutive d).
// ---------------------------------------------------------------------------
__global__ __launch_bounds__(256) void fold_kernel(
    const float* __restrict__ t,        // [B, HIDDEN]
    const float* __restrict__ W_patch,  // [HIDDEN, PATCH_DIM]
    float* __restrict__ v)              // [B, PATCH_DIM]
{
    const int b = blockIdx.x;
    __shared__ float t_sh[HIDDEN];
    for (int h = threadIdx.x; h < HIDDEN; h += 256)
        t_sh[h] = t[(size_t)b * HIDDEN + h];
    __syncthreads();

    float acc0 = 0.f, acc1 = 0.f, acc2 = 0.f, acc3 = 0.f;
    const int d0 = threadIdx.x;
    for (int h = 0; h < HIDDEN; ++h) {
        const float th = t_sh[h];
        const float* w = W_patch + (size_t)h * PATCH_DIM;
        acc0 += th * w[d0];
        acc1 += th * w[d0 + 256];
        acc2 += th * w[d0 + 512];
        acc3 += th * w[d0 + 768];
    }
    float* vb = v + (size_t)b * PATCH_DIM;
    vb[d0]       = acc0;
    vb[d0 + 256] = acc1;
    vb[d0 + 512] = acc2;
    vb[d0 + 768] = acc3;
}

// ---------------------------------------------------------------------------
// Kernel C (dominant): scores[b,n] = patches[b,n,:] . v[b,:] + bias[b]
// One wave (64 lanes) per row; 4x float4 per lane (1024 floats / row).
// Grid-strided: 2048 blocks x 256 threads = 8192 waves for 131072 rows.
// ---------------------------------------------------------------------------
__global__ __launch_bounds__(256) void score_kernel(
    const float* __restrict__ patches,  // [B*N, PATCH_DIM]
    const float* __restrict__ v,        // [B, PATCH_DIM]
    const float* __restrict__ bias,     // [B]
    float* __restrict__ out,            // [B*N]
    int total_rows)
{
    const int lane = threadIdx.x & 63;
    const int gwid = (blockIdx.x * blockDim.x + threadIdx.x) >> 6;
    const int nwaves = (gridDim.x * blockDim.x) >> 6;

    for (int row = gwid; row < total_rows; row += nwaves) {
        const int b = row >> 12;  // row / N_DIM (N_DIM = 4096)
        const float4* __restrict__ p =
            reinterpret_cast<const float4*>(patches + (size_t)row * PATCH_DIM);
        const float4* __restrict__ vv =
            reinterpret_cast<const float4*>(v + (size_t)b * PATCH_DIM);

        float acc = 0.f;
        #pragma unroll
        for (int k = 0; k < 4; ++k) {
            float4 a = p[lane + 64 * k];
            float4 w = vv[lane + 64 * k];
            acc += a.x * w.x + a.y * w.y + a.z * w.z + a.w * w.w;
        }

        #pragma unroll
        for (int off = 32; off > 0; off >>= 1)
            acc += __shfl_xor(acc, off, 64);

        if (lane == 0) out[row] = acc + bias[b];
    }
}

extern "C" void kernel_launch(void* const* d_in, const int* in_sizes, int n_in,
                              void* d_out, int out_size, void* d_ws, size_t ws_size,
                              hipStream_t stream) {
    const float* patches = (const float*)d_in[0];  // [B, N, PATCH_DIM]
    const float* text    = (const float*)d_in[1];  // [B, TEXT_DIM]
    const float* W_patch = (const float*)d_in[2];  // [HIDDEN, PATCH_DIM]
    const float* b_patch = (const float*)d_in[3];  // [HIDDEN]
    const float* W_text  = (const float*)d_in[4];  // [HIDDEN, TEXT_DIM]
    const float* b_text  = (const float*)d_in[5];  // [HIDDEN]
    float* out = (float*)d_out;                    // [B, N]

    // Workspace layout (floats): t [B*HIDDEN], v [B*PATCH_DIM], bias [B]
    float* t_ws    = (float*)d_ws;
    float* v_ws    = t_ws + B_DIM * HIDDEN;
    float* bias_ws = v_ws + B_DIM * PATCH_DIM;

    text_proj_kernel<<<B_DIM, 256, 0, stream>>>(text, W_text, b_text, b_patch,
                                                t_ws, bias_ws);
    fold_kernel<<<B_DIM, 256, 0, stream>>>(t_ws, W_patch, v_ws);

    const int total_rows = B_DIM * N_DIM;
    score_kernel<<<2048, 256, 0, stream>>>(patches, v_ws, bias_ws, out,
                                           total_rows);
}

// Round 2
// 112.491 us; speedup vs baseline: 1.7738x; 1.7738x over previous
//
#include <hip/hip_runtime.h>

// Problem dims (fixed by reference)
#define B_DIM 32
#define N_DIM 4096
#define PATCH_DIM 1024
#define TEXT_DIM 768
#define HIDDEN 512

typedef float f32x4 __attribute__((ext_vector_type(4)));

__device__ __forceinline__ float dot4(f32x4 a, f32x4 b) {
    return a.x * b.x + a.y * b.y + a.z * b.z + a.w * b.w;
}

// ---------------------------------------------------------------------------
// Kernel A: t[b,h] = text[b,:] . W_text[h,:] + b_text[h]
// grid (32 b, 8 h-chunks), 256 threads. One wave per h, 16 h per wave.
// text row (768 floats = 3 f32x4/lane) cached in registers across the h loop.
// ---------------------------------------------------------------------------
__global__ __launch_bounds__(256) void text_proj_kernel(
    const float* __restrict__ text,     // [B, TEXT_DIM]
    const float* __restrict__ W_text,   // [HIDDEN, TEXT_DIM]
    const float* __restrict__ b_text,   // [HIDDEN]
    float* __restrict__ t_out)          // [B, HIDDEN]
{
    const int b    = blockIdx.x;
    const int lane = threadIdx.x & 63;
    const int hbase = blockIdx.y * 64 + (threadIdx.x >> 6) * 16;

    const f32x4* tx4 = (const f32x4*)(text + (size_t)b * TEXT_DIM);
    const f32x4 t0 = tx4[lane], t1 = tx4[lane + 64], t2 = tx4[lane + 128];

    #pragma unroll 2
    for (int i = 0; i < 16; ++i) {
        const int h = hbase + i;
        const f32x4* wr = (const f32x4*)(W_text + (size_t)h * TEXT_DIM);
        float s = dot4(t0, wr[lane]) + dot4(t1, wr[lane + 64])
                + dot4(t2, wr[lane + 128]);
        #pragma unroll
        for (int off = 32; off; off >>= 1)
            s += __shfl_xor(s, off, 64);
        if (lane == 0)
            t_out[(size_t)b * HIDDEN + h] = s + b_text[h];
    }
}

// ---------------------------------------------------------------------------
// Kernel B: v[b,d] = sum_h t[b,h] * W_patch[h,d]; bias[b] = t[b,:].b_patch
// grid (32 b, 4 d-chunks), 256 threads. t[b] staged in LDS; h-loop with 4
// independent accumulators + unroll 16 for load ILP. dc==0 blocks do bias.
// ---------------------------------------------------------------------------
__global__ __launch_bounds__(256) void fold_kernel(
    const float* __restrict__ t,        // [B, HIDDEN]
    const float* __restrict__ W_patch,  // [HIDDEN, PATCH_DIM]
    const float* __restrict__ b_patch,  // [HIDDEN]
    float* __restrict__ v,              // [B, PATCH_DIM]
    float* __restrict__ bias_out)       // [B]
{
    const int b   = blockIdx.x;
    const int dc  = blockIdx.y;
    const int tid = threadIdx.x;

    __shared__ float t_sh[HIDDEN];
    t_sh[tid]       = t[(size_t)b * HIDDEN + tid];
    t_sh[tid + 256] = t[(size_t)b * HIDDEN + tid + 256];
    __syncthreads();

    const int d = dc * 256 + tid;
    const float* wp = W_patch + d;

    float a0 = 0.f, a1 = 0.f, a2 = 0.f, a3 = 0.f;
    #pragma unroll 4
    for (int h = 0; h < HIDDEN; h += 4) {
        a0 = fmaf(t_sh[h + 0], wp[(size_t)(h + 0) * PATCH_DIM], a0);
        a1 = fmaf(t_sh[h + 1], wp[(size_t)(h + 1) * PATCH_DIM], a1);
        a2 = fmaf(t_sh[h + 2], wp[(size_t)(h + 2) * PATCH_DIM], a2);
        a3 = fmaf(t_sh[h + 3], wp[(size_t)(h + 3) * PATCH_DIM], a3);
    }
    v[(size_t)b * PATCH_DIM + d] = (a0 + a1) + (a2 + a3);

    if (dc == 0) {
        float partial = t_sh[tid] * b_patch[tid]
                      + t_sh[tid + 256] * b_patch[tid + 256];
        #pragma unroll
        for (int off = 32; off; off >>= 1)
            partial += __shfl_xor(partial, off, 64);
        __shared__ float wsum[4];
        if ((tid & 63) == 0) wsum[tid >> 6] = partial;
        __syncthreads();
        if (tid == 0)
            bias_out[b] = (wsum[0] + wsum[1]) + (wsum[2] + wsum[3]);
    }
}

// ---------------------------------------------------------------------------
// Kernel C (dominant, streams 512 MB of patches):
//   scores[b,n] = patches[b,n,:] . v[b,:] + bias[b]
// 2048 blocks x 256 threads = 8192 waves; wave g owns rows [g*16, g*16+16),
// all within one b (4096 rows per b, 256 waves per b). v[b] lives in 16
// registers for the whole wave. Rows processed 4 at a time: 16 nontemporal
// float4 loads in flight, 4 independent shuffle-reduce chains, one float4
// store per group from lane 0.
// ---------------------------------------------------------------------------
__global__ __launch_bounds__(256) void score_kernel(
    const float* __restrict__ patches,  // [B*N, PATCH_DIM]
    const float* __restrict__ v,        // [B, PATCH_DIM]
    const float* __restrict__ bias,     // [B]
    float* __restrict__ out)            // [B*N]
{
    const int lane = threadIdx.x & 63;
    const int g    = blockIdx.x * 4 + (threadIdx.x >> 6);  // 0..8191
    const int b    = g >> 8;          // 256 waves per b
    const int row0 = g << 4;          // 16 rows per wave

    const f32x4* vv = (const f32x4*)(v + (size_t)b * PATCH_DIM);
    const f32x4 v0 = vv[lane], v1 = vv[lane + 64],
                v2 = vv[lane + 128], v3 = vv[lane + 192];
    const float bs = bias[b];

    for (int i = 0; i < 16; i += 4) {
        const f32x4* p0 = (const f32x4*)(patches + (size_t)(row0 + i + 0) * PATCH_DIM);
        const f32x4* p1 = (const f32x4*)(patches + (size_t)(row0 + i + 1) * PATCH_DIM);
        const f32x4* p2 = (const f32x4*)(patches + (size_t)(row0 + i + 2) * PATCH_DIM);
        const f32x4* p3 = (const f32x4*)(patches + (size_t)(row0 + i + 3) * PATCH_DIM);

        f32x4 a00 = __builtin_nontemporal_load(p0 + lane);
        f32x4 a01 = __builtin_nontemporal_load(p0 + lane + 64);
        f32x4 a02 = __builtin_nontemporal_load(p0 + lane + 128);
        f32x4 a03 = __builtin_nontemporal_load(p0 + lane + 192);
        f32x4 a10 = __builtin_nontemporal_load(p1 + lane);
        f32x4 a11 = __builtin_nontemporal_load(p1 + lane + 64);
        f32x4 a12 = __builtin_nontemporal_load(p1 + lane + 128);
        f32x4 a13 = __builtin_nontemporal_load(p1 + lane + 192);
        f32x4 a20 = __builtin_nontemporal_load(p2 + lane);
        f32x4 a21 = __builtin_nontemporal_load(p2 + lane + 64);
        f32x4 a22 = __builtin_nontemporal_load(p2 + lane + 128);
        f32x4 a23 = __builtin_nontemporal_load(p2 + lane + 192);
        f32x4 a30 = __builtin_nontemporal_load(p3 + lane);
        f32x4 a31 = __builtin_nontemporal_load(p3 + lane + 64);
        f32x4 a32 = __builtin_nontemporal_load(p3 + lane + 128);
        f32x4 a33 = __builtin_nontemporal_load(p3 + lane + 192);

        float s0 = dot4(a00, v0) + dot4(a01, v1) + dot4(a02, v2) + dot4(a03, v3);
        float s1 = dot4(a10, v0) + dot4(a11, v1) + dot4(a12, v2) + dot4(a13, v3);
        float s2 = dot4(a20, v0) + dot4(a21, v1) + dot4(a22, v2) + dot4(a23, v3);
        float s3 = dot4(a30, v0) + dot4(a31, v1) + dot4(a32, v2) + dot4(a33, v3);

        // 4 independent butterfly chains, interleaved to hide shfl latency
        #pragma unroll
        for (int off = 32; off; off >>= 1) {
            s0 += __shfl_xor(s0, off, 64);
            s1 += __shfl_xor(s1, off, 64);
            s2 += __shfl_xor(s2, off, 64);
            s3 += __shfl_xor(s3, off, 64);
        }

        if (lane == 0) {
            f32x4 o = { s0 + bs, s1 + bs, s2 + bs, s3 + bs };
            *(f32x4*)(out + row0 + i) = o;
        }
    }
}

extern "C" void kernel_launch(void* const* d_in, const int* in_sizes, int n_in,
                              void* d_out, int out_size, void* d_ws, size_t ws_size,
                              hipStream_t stream) {
    const float* patches = (const float*)d_in[0];  // [B, N, PATCH_DIM]
    const float* text    = (const float*)d_in[1];  // [B, TEXT_DIM]
    const float* W_patch = (const float*)d_in[2];  // [HIDDEN, PATCH_DIM]
    const float* b_patch = (const float*)d_in[3];  // [HIDDEN]
    const float* W_text  = (const float*)d_in[4];  // [HIDDEN, TEXT_DIM]
    const float* b_text  = (const float*)d_in[5];  // [HIDDEN]
    float* out = (float*)d_out;                    // [B, N]

    // Workspace layout (floats): t [B*HIDDEN], v [B*PATCH_DIM], bias [B]
    float* t_ws    = (float*)d_ws;
    float* v_ws    = t_ws + B_DIM * HIDDEN;
    float* bias_ws = v_ws + B_DIM * PATCH_DIM;

    text_proj_kernel<<<dim3(B_DIM, 8), 256, 0, stream>>>(text, W_text, b_text, t_ws);
    fold_kernel<<<dim3(B_DIM, 4), 256, 0, stream>>>(t_ws, W_patch, b_patch, v_ws, bias_ws);
    score_kernel<<<2048, 256, 0, stream>>>(patches, v_ws, bias_ws, out);
}